// Round 1
// baseline (334.414 us; speedup 1.0000x reference)
//
#include <hip/hip_runtime.h>
#include <hip/hip_bf16.h>

// PointPillarsScatter: out[b][c][y][x] = vf[p][c] where coords[p]=(b,0,y,x),
// last p wins on duplicates (numpy scatter semantics); 0 elsewhere.
// B=4, C=64, NY=512, NX=512 fixed by the problem.

#define NXC 512
#define NYC 512
#define BC 4
#define CC 64
#define SLOTS_PER_BATCH (NXC * NYC)        // 262144 = 2^18
#define TOTAL_SLOTS (BC * SLOTS_PER_BATCH) // 1048576

// Phase 2: deterministic "last pillar wins" via atomicMax on pillar index.
__global__ void build_winner_kernel(const int* __restrict__ coords,
                                    int* __restrict__ winner, int P) {
    int p = blockIdx.x * blockDim.x + threadIdx.x;
    if (p >= P) return;
    int4 c = ((const int4*)coords)[p];      // (b, z, y, x)
    int flat = c.x * SLOTS_PER_BATCH + c.z * NXC + c.w;
    atomicMax(&winner[flat], p);
}

// Phase 3: inverse-map gather. One thread per (b,y,x) slot; writes all 64
// channels with coalesced stores (consecutive threads -> consecutive x).
__global__ void scatter_out_kernel(const float* __restrict__ vf,
                                   const int* __restrict__ winner,
                                   float* __restrict__ out) {
    int slot = blockIdx.x * blockDim.x + threadIdx.x;
    int b = slot >> 18;                      // / SLOTS_PER_BATCH
    int rem = slot & (SLOTS_PER_BATCH - 1);  // y*NX + x
    int p = winner[slot];

    float* obase = out + (size_t)b * CC * SLOTS_PER_BATCH + rem;
    const float4* v4 = (const float4*)(vf + (size_t)p * CC);

    #pragma unroll
    for (int j = 0; j < 16; ++j) {
        float4 v = make_float4(0.f, 0.f, 0.f, 0.f);
        if (p >= 0) v = v4[j];               // 16B gather, 4 full lines/pillar
        obase[(size_t)(4 * j + 0) * SLOTS_PER_BATCH] = v.x;
        obase[(size_t)(4 * j + 1) * SLOTS_PER_BATCH] = v.y;
        obase[(size_t)(4 * j + 2) * SLOTS_PER_BATCH] = v.z;
        obase[(size_t)(4 * j + 3) * SLOTS_PER_BATCH] = v.w;
    }
}

extern "C" void kernel_launch(void* const* d_in, const int* in_sizes, int n_in,
                              void* d_out, int out_size, void* d_ws, size_t ws_size,
                              hipStream_t stream) {
    const float* vf    = (const float*)d_in[0];   // [P, 64] float32
    const int* coords  = (const int*)d_in[1];     // [P, 4] int32 (b,z,y,x)
    int P = in_sizes[0] / CC;

    int* winner = (int*)d_ws;                     // [TOTAL_SLOTS] int32 (4 MiB)
    float* out  = (float*)d_out;                  // [4,64,512,512] float32

    // Phase 1: winner = -1 everywhere (0xFF bytes == -1 as int32).
    hipMemsetAsync(winner, 0xFF, (size_t)TOTAL_SLOTS * sizeof(int), stream);

    // Phase 2: last-write-wins winner table.
    build_winner_kernel<<<(P + 255) / 256, 256, 0, stream>>>(coords, winner, P);

    // Phase 3: dense coalesced output generation (writes every element).
    scatter_out_kernel<<<TOTAL_SLOTS / 256, 256, 0, stream>>>(vf, winner, out);
}

// Round 3
// 302.421 us; speedup vs baseline: 1.1058x; 1.1058x over previous
//
#include <hip/hip_runtime.h>
#include <hip/hip_bf16.h>

// PointPillarsScatter: out[b][c][y][x] = vf[p][c] where coords[p]=(b,0,y,x),
// last p wins on duplicates (numpy scatter semantics); 0 elsewhere.
// B=4, C=64, NY=512, NX=512 fixed by the problem.

#define NXC 512
#define NYC 512
#define BC 4
#define CC 64
#define SLOTS_PER_BATCH (NXC * NYC)        // 262144 = 2^18
#define TOTAL_SLOTS (BC * SLOTS_PER_BATCH) // 1048576

typedef float vf4 __attribute__((ext_vector_type(4)));  // native vec for nt-store

// Phase 2: deterministic "last pillar wins" via atomicMax on pillar index.
__global__ void build_winner_kernel(const int* __restrict__ coords,
                                    int* __restrict__ winner, int P) {
    int p = blockIdx.x * blockDim.x + threadIdx.x;
    if (p >= P) return;
    int4 c = ((const int4*)coords)[p];      // (b, z, y, x)
    int flat = c.x * SLOTS_PER_BATCH + c.z * NXC + c.w;
    atomicMax(&winner[flat], p);
}

// Phase 3: inverse-map gather, 4 slots per thread, float4 transposed stores.
// Consecutive threads -> consecutive 16B chunks along x => 1KiB/wave-store.
__global__ __launch_bounds__(256) void scatter_out_kernel(
        const float* __restrict__ vf,
        const int* __restrict__ winner,
        float* __restrict__ out) {
    int t = blockIdx.x * blockDim.x + threadIdx.x;   // 262144 threads
    int slot0 = t << 2;                              // 4 slots/thread, same batch
    int b = slot0 >> 18;
    int rem = slot0 & (SLOTS_PER_BATCH - 1);

    int4 w = ((const int4*)winner)[t];               // coalesced 16B winner read

    float* obase = out + (size_t)b * (CC * SLOTS_PER_BATCH) + rem;
    const vf4* v0 = (const vf4*)(vf + (size_t)w.x * CC);
    const vf4* v1 = (const vf4*)(vf + (size_t)w.y * CC);
    const vf4* v2 = (const vf4*)(vf + (size_t)w.z * CC);
    const vf4* v3 = (const vf4*)(vf + (size_t)w.w * CC);

    const vf4 z4 = (vf4)(0.f);
    #pragma unroll
    for (int j = 0; j < 16; ++j) {
        vf4 a = z4, bb = z4, cc = z4, dd = z4;
        if (w.x >= 0) a  = v0[j];                    // 16B random gathers,
        if (w.y >= 0) bb = v1[j];                    // 4 full lines/pillar,
        if (w.z >= 0) cc = v2[j];                    // exec-masked lanes
        if (w.w >= 0) dd = v3[j];                    // generate no traffic

        // 4x4 transpose: rows = channels 4j..4j+3, cols = x..x+3
        vf4* s0 = (vf4*)(obase + (size_t)(4 * j + 0) * SLOTS_PER_BATCH);
        vf4* s1 = (vf4*)(obase + (size_t)(4 * j + 1) * SLOTS_PER_BATCH);
        vf4* s2 = (vf4*)(obase + (size_t)(4 * j + 2) * SLOTS_PER_BATCH);
        vf4* s3 = (vf4*)(obase + (size_t)(4 * j + 3) * SLOTS_PER_BATCH);
        vf4 r0 = {a.x, bb.x, cc.x, dd.x};
        vf4 r1 = {a.y, bb.y, cc.y, dd.y};
        vf4 r2 = {a.z, bb.z, cc.z, dd.z};
        vf4 r3 = {a.w, bb.w, cc.w, dd.w};
        __builtin_nontemporal_store(r0, s0);
        __builtin_nontemporal_store(r1, s1);
        __builtin_nontemporal_store(r2, s2);
        __builtin_nontemporal_store(r3, s3);
    }
}

extern "C" void kernel_launch(void* const* d_in, const int* in_sizes, int n_in,
                              void* d_out, int out_size, void* d_ws, size_t ws_size,
                              hipStream_t stream) {
    const float* vf    = (const float*)d_in[0];   // [P, 64] float32
    const int* coords  = (const int*)d_in[1];     // [P, 4] int32 (b,z,y,x)
    int P = in_sizes[0] / CC;

    int* winner = (int*)d_ws;                     // [TOTAL_SLOTS] int32 (4 MiB)
    float* out  = (float*)d_out;                  // [4,64,512,512] float32

    // Phase 1: winner = -1 everywhere (0xFF bytes == -1 as int32).
    (void)hipMemsetAsync(winner, 0xFF, (size_t)TOTAL_SLOTS * sizeof(int), stream);

    // Phase 2: last-write-wins winner table.
    build_winner_kernel<<<(P + 255) / 256, 256, 0, stream>>>(coords, winner, P);

    // Phase 3: dense coalesced output generation (writes every element).
    scatter_out_kernel<<<TOTAL_SLOTS / 4 / 256, 256, 0, stream>>>(vf, winner, out);
}

// Round 4
// 299.517 us; speedup vs baseline: 1.1165x; 1.0097x over previous
//
#include <hip/hip_runtime.h>
#include <hip/hip_bf16.h>

// PointPillarsScatter: out[b][c][y][x] = vf[p][c] where coords[p]=(b,0,y,x),
// last p wins on duplicates (numpy scatter semantics); 0 elsewhere.
// B=4, C=64, NY=512, NX=512 fixed by the problem.

#define NXC 512
#define NYC 512
#define BC 4
#define CC 64
#define SLOTS_PER_BATCH (NXC * NYC)        // 262144 = 2^18
#define TOTAL_SLOTS (BC * SLOTS_PER_BATCH) // 1048576

typedef float vf4 __attribute__((ext_vector_type(4)));  // native vec for nt-store

// Phase 2: deterministic "last pillar wins" via atomicMax on pillar index.
__global__ void build_winner_kernel(const int* __restrict__ coords,
                                    int* __restrict__ winner, int P) {
    int p = blockIdx.x * blockDim.x + threadIdx.x;
    if (p >= P) return;
    int4 c = ((const int4*)coords)[p];      // (b, z, y, x)
    int flat = c.x * SLOTS_PER_BATCH + c.z * NXC + c.w;
    atomicMax(&winner[flat], p);
}

// Phase 3: inverse-map gather. Each thread owns 4 consecutive x-slots and a
// 32-channel HALF (blockIdx parity) => grid 2048 blocks, up to 32 waves/CU.
// Stores: 16B/lane, wave-contiguous 1KiB per instr, NT (write-once).
// Gathers: one 128B line per pillar-half per thread, exec-masked (empty
// lanes generate no traffic; ~11% occupancy).
__global__ __launch_bounds__(256) void scatter_out_kernel(
        const float* __restrict__ vf,
        const int* __restrict__ winner,
        float* __restrict__ out) {
    int blk = blockIdx.x;
    int h   = blk & 1;                               // channel half: 0 or 1
    int tq  = ((blk >> 1) << 8) + threadIdx.x;       // slot-quad id, 0..262143
    int b   = tq >> 16;                              // batch
    int rem = (tq << 2) & (SLOTS_PER_BATCH - 1);     // y*NX + x

    int4 w = ((const int4*)winner)[tq];              // coalesced 16B winner read

    float* obase = out + (size_t)b * (CC * SLOTS_PER_BATCH)
                       + (size_t)(h << 5) * SLOTS_PER_BATCH + rem;
    const int coff = h << 3;                         // half offset in float4s
    const vf4* v0 = (const vf4*)(vf + (size_t)w.x * CC) + coff;
    const vf4* v1 = (const vf4*)(vf + (size_t)w.y * CC) + coff;
    const vf4* v2 = (const vf4*)(vf + (size_t)w.z * CC) + coff;
    const vf4* v3 = (const vf4*)(vf + (size_t)w.w * CC) + coff;

    const vf4 z4 = (vf4)(0.f);
    #pragma unroll
    for (int j = 0; j < 8; ++j) {                    // 8 channel-quads in half
        vf4 a = z4, bb = z4, cc = z4, dd = z4;
        if (w.x >= 0) a  = v0[j];
        if (w.y >= 0) bb = v1[j];
        if (w.z >= 0) cc = v2[j];
        if (w.w >= 0) dd = v3[j];

        // 4x4 transpose: rows = 4 channels, cols = 4 consecutive x
        vf4* s0 = (vf4*)(obase + (size_t)(4 * j + 0) * SLOTS_PER_BATCH);
        vf4* s1 = (vf4*)(obase + (size_t)(4 * j + 1) * SLOTS_PER_BATCH);
        vf4* s2 = (vf4*)(obase + (size_t)(4 * j + 2) * SLOTS_PER_BATCH);
        vf4* s3 = (vf4*)(obase + (size_t)(4 * j + 3) * SLOTS_PER_BATCH);
        vf4 r0 = {a.x, bb.x, cc.x, dd.x};
        vf4 r1 = {a.y, bb.y, cc.y, dd.y};
        vf4 r2 = {a.z, bb.z, cc.z, dd.z};
        vf4 r3 = {a.w, bb.w, cc.w, dd.w};
        __builtin_nontemporal_store(r0, s0);
        __builtin_nontemporal_store(r1, s1);
        __builtin_nontemporal_store(r2, s2);
        __builtin_nontemporal_store(r3, s3);
    }
}

extern "C" void kernel_launch(void* const* d_in, const int* in_sizes, int n_in,
                              void* d_out, int out_size, void* d_ws, size_t ws_size,
                              hipStream_t stream) {
    const float* vf    = (const float*)d_in[0];   // [P, 64] float32
    const int* coords  = (const int*)d_in[1];     // [P, 4] int32 (b,z,y,x)
    int P = in_sizes[0] / CC;

    int* winner = (int*)d_ws;                     // [TOTAL_SLOTS] int32 (4 MiB)
    float* out  = (float*)d_out;                  // [4,64,512,512] float32

    // Phase 1: winner = -1 everywhere (0xFF bytes == -1 as int32).
    (void)hipMemsetAsync(winner, 0xFF, (size_t)TOTAL_SLOTS * sizeof(int), stream);

    // Phase 2: last-write-wins winner table.
    build_winner_kernel<<<(P + 255) / 256, 256, 0, stream>>>(coords, winner, P);

    // Phase 3: dense coalesced output generation (writes every element).
    // 2048 blocks: even/odd pairs cover channel halves of 256 slot-quads.
    scatter_out_kernel<<<(TOTAL_SLOTS / 4 / 256) * 2, 256, 0, stream>>>(vf, winner, out);
}